// Round 15
// baseline (635.929 us; speedup 1.0000x reference)
//
#include <hip/hip_runtime.h>
#include <float.h>

#define BATCH 4

typedef _Float16 half8 __attribute__((ext_vector_type(8)));
typedef float f32x16 __attribute__((ext_vector_type(16)));
typedef float f32x2 __attribute__((ext_vector_type(2)));

// ================= MFMA path (R11 structure, ablation round) =================
// D[p,q] = |p|^2 + |q|^2 - 2 p.q  via K=13 fp16 slots (exact split).
// A rows = dst (scan) points, B cols = src (owned) points. Point-major forms.

__global__ void prep_fp16(const float* __restrict__ x1, const float* __restrict__ x2,
                          _Float16* __restrict__ pa1, _Float16* __restrict__ pb1,
                          _Float16* __restrict__ pa2, _Float16* __restrict__ pb2,
                          float* __restrict__ out, int n1, int n2, int outn) {
    const int i = blockIdx.x * blockDim.x + threadIdx.x;
    const _Float16 one = (_Float16)1.0f, zro = (_Float16)0.0f;

    #pragma unroll
    for (int which = 0; which < 2; ++which) {
        const int n = which ? n2 : n1;
        if (i >= n) continue;
        const float* xp = (which ? x2 : x1) + 3 * (size_t)i;
        _Float16* pa = (which ? pa2 : pa1) + 16 * (size_t)i;
        _Float16* pb = (which ? pb2 : pb1) + 16 * (size_t)i;

        const float x = xp[0], y = xp[1], z = xp[2];
        const _Float16 hx = (_Float16)x, hy = (_Float16)y, hz = (_Float16)z;
        const _Float16 ex = (_Float16)(x - (float)hx);
        const _Float16 ey = (_Float16)(y - (float)hy);
        const _Float16 ez = (_Float16)(z - (float)hz);
        const float ps = fmaf(x, x, fmaf(y, y, z * z));
        const _Float16 ph = (_Float16)ps;
        const _Float16 pe = (_Float16)(ps - (float)ph);
        const _Float16 tx = (_Float16)(-2.0f * (float)hx);
        const _Float16 ty = (_Float16)(-2.0f * (float)hy);
        const _Float16 tz = (_Float16)(-2.0f * (float)hz);
        const _Float16 ux = (_Float16)(-2.0f * (float)ex);
        const _Float16 uy = (_Float16)(-2.0f * (float)ey);
        const _Float16 uz = (_Float16)(-2.0f * (float)ez);

        const half8 a0 = (half8){hx, hy, hz, hx, hy, hz, ex, ey};
        const half8 a1 = (half8){ez, ph, pe, one, one, zro, zro, zro};
        const half8 b0 = (half8){tx, ty, tz, ux, uy, uz, tx, ty};
        const half8 b1 = (half8){tz, one, one, ph, pe, zro, zro, zro};

        *(half8*)(pa)     = a0;
        *(half8*)(pa + 8) = a1;
        *(half8*)(pb)     = b0;
        *(half8*)(pb + 8) = b1;
    }
    if (i < outn) out[i] = FLT_MAX;
}

__device__ inline float min16_into(float r, const f32x16 d) {
    const float t0 = fminf(fminf(d[0],  d[1]),  d[2]);
    const float t1 = fminf(fminf(d[3],  d[4]),  d[5]);
    const float t2 = fminf(fminf(d[6],  d[7]),  d[8]);
    const float t3 = fminf(fminf(d[9],  d[10]), d[11]);
    const float t4 = fminf(fminf(d[12], d[13]), d[14]);
    const float u0 = fminf(fminf(t0, t1), t2);
    const float u1 = fminf(fminf(t3, t4), d[15]);
    return fminf(fminf(r, u0), u1);
}

// ===================== ABLATION KERNEL (R15) =====================
// R11-R14: four different staging schemes all gave main ~= 30us. Stop
// optimizing, measure the marginal cost of each phase (skill: ablate first).
// VARIANT 0: FULL — real output (atomicMin idempotent across REPEATs).
// VARIANT 1: staging + ds_read only (XOR keep-alive; no MFMA/min).
// VARIANT 2: staging + ds_read + MFMA (d[0] keep-alive; no min tree).
// VARIANT 3: stage ONCE, then ds_read + MFMA + min   (global staging removed).
// VARIANT 4: stage ONCE, no ds_read; p-varying reg a  (LDS read also removed).
// Deltas: staging=V0-V3, ds_read=V3-V4, min-tree=V0-V2, compute floor=V4.
// REPEAT=8 makes each dispatch > the 41us ws-poison fills so all five rows
// appear in the top-5 rocprof table.
template<int NJ, int VARIANT, int REPEAT>
__global__ __launch_bounds__(256) void chamfer_abl(
        const _Float16* __restrict__ pa1, const _Float16* __restrict__ pb1,
        const _Float16* __restrict__ pa2, const _Float16* __restrict__ pb2,
        float* __restrict__ outbase, int N) {
    constexpr int IT = 2;
    __shared__ uint4 sA[512];   // 8 KiB

    const int tid  = threadIdx.x;
    const int lane = tid & 63;
    const int w    = tid >> 6;

    int bid = blockIdx.x;
    const int RB      = N / 256;
    const int per_dir = BATCH * RB * NJ;
    const int dir = bid / per_dir;   bid %= per_dir;
    const int b   = bid / (RB * NJ); bid %= (RB * NJ);
    const int cb  = bid / NJ;
    const int js  = bid % NJ;

    const _Float16* pstage = dir ? pa1 : pa2;
    const _Float16* pheld  = dir ? pb2 : pb1;
    float* outd = outbase + (size_t)dir * BATCH * N + (size_t)b * N;

    const int colbase = cb * 256 + w * 64;
    const uint4* gh = (const uint4*)pheld;
    half8 bf[IT];
    #pragma unroll
    for (int it = 0; it < IT; ++it) {
        const int c = colbase + it * 32 + (lane & 31);
        bf[it] = __builtin_bit_cast(half8, gh[(size_t)(b * N + c) * 2 + (lane >> 5)]);
    }

    float rmin[IT];
    #pragma unroll
    for (int it = 0; it < IT; ++it) rmin[it] = FLT_MAX;
    unsigned dummy_u = 0u;
    float dummy = FLT_MAX;

    f32x16 cz;
    #pragma unroll
    for (int e = 0; e < 16; ++e) cz[e] = 0.0f;

    const int jseg   = N / NJ;
    const int stages = jseg / 256;
    const uint4* gs  = (const uint4*)pstage;
    const int t = tid >> 5, col = tid & 31;

    for (int rep = 0; rep < REPEAT; ++rep) {
        for (int s = 0; s < stages; ++s) {
            const bool do_stage = (VARIANT >= 3) ? (rep == 0 && s == 0) : true;
            uint4 v0, v1;
            if (do_stage) {
                const size_t q = (size_t)(b * N + js * jseg + s * 256 + tid) * 2;
                v0 = gs[q]; v1 = gs[q + 1];
            }
            __syncthreads();
            if (do_stage) {
                sA[t * 64 + col]      = v0;
                sA[t * 64 + 32 + col] = v1;
            }
            __syncthreads();

            #pragma unroll
            for (int p = 0; p < 8; ++p) {
                if constexpr (VARIANT == 1) {
                    const uint4 au = sA[p * 64 + lane];
                    dummy_u ^= au.x ^ au.y ^ au.z ^ au.w;   // keep b128 live
                } else {
                    half8 a;
                    if constexpr (VARIANT == 4) {
                        uint4 au = __builtin_bit_cast(uint4, bf[0]);
                        au.x ^= (unsigned)(p * 0x9E3779B9u);  // un-hoistable
                        a = __builtin_bit_cast(half8, au);
                    } else {
                        a = __builtin_bit_cast(half8, sA[p * 64 + lane]);
                    }
                    #pragma unroll
                    for (int it = 0; it < IT; ++it) {
                        const f32x16 d = __builtin_amdgcn_mfma_f32_32x32x16_f16(a, bf[it], cz, 0, 0, 0);
                        if constexpr (VARIANT == 2) {
                            dummy = fminf(dummy, d[0]);      // keep MFMA live
                        } else {
                            rmin[it] = min16_into(rmin[it], d);
                        }
                    }
                }
            }
        }
    }

    if constexpr (VARIANT == 1) dummy = fminf(dummy, (float)(dummy_u & 63u));

    #pragma unroll
    for (int it = 0; it < IT; ++it) {
        float v = fminf(rmin[it], __shfl_xor(rmin[it], 32, 64));
        v = fminf(v, dummy);             // no-op for V0 (dummy=FLT_MAX)
        v = fmaxf(v, 0.0f);
        if (lane < 32)
            atomicMin((int*)&outd[colbase + it * 32 + lane], __float_as_int(v));
    }
}

// ================= fallback: R6 pk-fma path =================
__global__ void chamfer_prep(const float* __restrict__ xyz1,
                             const float* __restrict__ xyz2,
                             float4* __restrict__ pk1,
                             float4* __restrict__ pk2,
                             float* __restrict__ out,
                             int n1, int n2, int out_n) {
    int i = blockIdx.x * blockDim.x + threadIdx.x;
    if (i < n1) {
        float x = xyz1[3 * (size_t)i], y = xyz1[3 * (size_t)i + 1], z = xyz1[3 * (size_t)i + 2];
        pk1[i] = make_float4(-2.f * x, -2.f * y, -2.f * z, fmaf(x, x, fmaf(y, y, z * z)));
    }
    if (i < n2) {
        float x = xyz2[3 * (size_t)i], y = xyz2[3 * (size_t)i + 1], z = xyz2[3 * (size_t)i + 2];
        pk2[i] = make_float4(-2.f * x, -2.f * y, -2.f * z, fmaf(x, x, fmaf(y, y, z * z)));
    }
    if (i < out_n) out[i] = FLT_MAX;
}

template<int TPB, int CHUNK, int P>
__global__ __launch_bounds__(TPB) void chamfer_fused(
        const float* __restrict__ xyz1, const float* __restrict__ xyz2,
        const float4* __restrict__ pk1, const float4* __restrict__ pk2,
        float* __restrict__ out, int N, int M, int blocks_dir0) {
    __shared__ float4 s[CHUNK];
    int bid = blockIdx.x;
    const int dir = (bid >= blocks_dir0) ? 1 : 0;
    if (dir) bid -= blocks_dir0;
    const int Nsrc = dir ? M : N;
    const int Mdst = dir ? N : M;
    const float* src   = dir ? xyz2 : xyz1;
    const float4* dstp = dir ? pk1  : pk2;
    float* outd        = dir ? (out + (size_t)BATCH * N) : out;
    const int YT = Nsrc / (TPB * P);
    const int Z  = Mdst / CHUNK;
    const int b  = bid / (YT * Z);
    const int r  = bid % (YT * Z);
    const int yt = r / Z;
    const int z  = r % Z;
    const float4* dchunk = dstp + (size_t)b * Mdst + (size_t)z * CHUNK;
    for (int t = threadIdx.x; t < CHUNK / 2; t += TPB) {
        const float4 q0 = dchunk[2 * t];
        const float4 q1 = dchunk[2 * t + 1];
        s[2 * t]     = make_float4(q0.x, q1.x, q0.y, q1.y);
        s[2 * t + 1] = make_float4(q0.z, q1.z, q0.w, q1.w);
    }
    const int i0 = yt * (TPB * P) + threadIdx.x;
    f32x2 px[P], py[P], pz[P];
    float psq[P], m[P];
    #pragma unroll
    for (int k = 0; k < P; ++k) {
        const int i = i0 + k * TPB;
        const float* p = src + ((size_t)b * Nsrc + i) * 3;
        const float x = p[0], y = p[1], zc = p[2];
        px[k] = (f32x2){x, x}; py[k] = (f32x2){y, y}; pz[k] = (f32x2){zc, zc};
        psq[k] = fmaf(x, x, fmaf(y, y, zc * zc));
        m[k] = FLT_MAX;
    }
    __syncthreads();
    #pragma unroll 8
    for (int jj = 0; jj < CHUNK / 2; ++jj) {
        const float4 A = s[2 * jj];
        const float4 B = s[2 * jj + 1];
        const f32x2 xq = (f32x2){A.x, A.y};
        const f32x2 yq = (f32x2){A.z, A.w};
        const f32x2 zq = (f32x2){B.x, B.y};
        const f32x2 wq = (f32x2){B.z, B.w};
        #pragma unroll
        for (int k = 0; k < P; ++k) {
            const f32x2 e = __builtin_elementwise_fma(xq, px[k],
                             __builtin_elementwise_fma(yq, py[k],
                              __builtin_elementwise_fma(zq, pz[k], wq)));
            m[k] = fminf(fminf(m[k], e.x), e.y);
        }
    }
    #pragma unroll
    for (int k = 0; k < P; ++k) {
        const int i = i0 + k * TPB;
        const float d = fmaxf(psq[k] + m[k], 0.0f);
        atomicMin((int*)&outd[(size_t)b * Nsrc + i], __float_as_int(d));
    }
}

extern "C" void kernel_launch(void* const* d_in, const int* in_sizes, int n_in,
                              void* d_out, int out_size, void* d_ws, size_t ws_size,
                              hipStream_t stream) {
    const float* xyz1 = (const float*)d_in[0];
    const float* xyz2 = (const float*)d_in[1];
    float* out = (float*)d_out;

    const int N = in_sizes[0] / (BATCH * 3);  // 8192
    const int M = in_sizes[1] / (BATCH * 3);  // 8192
    const int n1 = BATCH * N, n2 = BATCH * M;

    constexpr int TPB = 256;
    constexpr int NJ = 8;
    constexpr int REPEAT = 8;

    const size_t need16   = ((size_t)n1 + (size_t)n2) * 64;   // packed forms (4MB)
    const size_t scr_off  = (size_t)16 << 20;                 // scratch at +16MB
    const size_t need_all = scr_off + (size_t)(n1 + n2) * sizeof(float);
    const bool mfma_ok = (N == M) && (N % (NJ * 256) == 0) &&
                         (ws_size >= need_all) && (need16 <= scr_off);

    if (mfma_ok) {
        _Float16* pa1 = (_Float16*)d_ws;
        _Float16* pb1 = pa1 + (size_t)n1 * 16;
        _Float16* pa2 = pb1 + (size_t)n1 * 16;
        _Float16* pb2 = pa2 + (size_t)n2 * 16;
        float* scratch = (float*)((char*)d_ws + scr_off);
        int prep_n = out_size > n1 ? out_size : n1;
        if (n2 > prep_n) prep_n = n2;
        prep_fp16<<<(prep_n + TPB - 1) / TPB, TPB, 0, stream>>>(
            xyz1, xyz2, pa1, pb1, pa2, pb2, out, n1, n2, out_size);

        const int grid = 2 * BATCH * (N / 256) * NJ;   // 2048
        // V0 = real output (idempotent across repeats)
        chamfer_abl<NJ, 0, REPEAT><<<grid, TPB, 0, stream>>>(pa1, pb1, pa2, pb2, out, N);
        // Diagnostics -> scratch
        chamfer_abl<NJ, 1, REPEAT><<<grid, TPB, 0, stream>>>(pa1, pb1, pa2, pb2, scratch, N);
        chamfer_abl<NJ, 2, REPEAT><<<grid, TPB, 0, stream>>>(pa1, pb1, pa2, pb2, scratch, N);
        chamfer_abl<NJ, 3, REPEAT><<<grid, TPB, 0, stream>>>(pa1, pb1, pa2, pb2, scratch, N);
        chamfer_abl<NJ, 4, REPEAT><<<grid, TPB, 0, stream>>>(pa1, pb1, pa2, pb2, scratch, N);
        return;
    }

    // fallback: R6 pk-fma path
    constexpr int CHUNK = 128;
    constexpr int P = 8;
    const size_t need = ((size_t)n1 + (size_t)n2) * sizeof(float4);
    if (ws_size >= need && (N % (TPB * P) == 0) && (M % (TPB * P) == 0) &&
        (N % CHUNK == 0) && (M % CHUNK == 0)) {
        float4* pk1 = (float4*)d_ws;
        float4* pk2 = pk1 + n1;
        int prep_n = out_size > n1 ? out_size : n1;
        if (n2 > prep_n) prep_n = n2;
        chamfer_prep<<<(prep_n + TPB - 1) / TPB, TPB, 0, stream>>>(
            xyz1, xyz2, pk1, pk2, out, n1, n2, out_size);
        const int blocks_dir0 = BATCH * (N / (TPB * P)) * (M / CHUNK);
        const int blocks_dir1 = BATCH * (M / (TPB * P)) * (N / CHUNK);
        chamfer_fused<TPB, CHUNK, P><<<blocks_dir0 + blocks_dir1, TPB, 0, stream>>>(
            xyz1, xyz2, pk1, pk2, out, N, M, blocks_dir0);
    }
}

// Round 16
// 33.873 us; speedup vs baseline: 18.7737x; 18.7737x over previous
//
#include <hip/hip_runtime.h>
#include <float.h>

#define BATCH 4

typedef _Float16 half4v __attribute__((ext_vector_type(4)));
typedef _Float16 half8 __attribute__((ext_vector_type(8)));
typedef float f32x16 __attribute__((ext_vector_type(16)));
typedef float f32x2 __attribute__((ext_vector_type(2)));

// ================= MFMA K=8 path (R16) =================
// E[j,i] = qs_j - 2 q_j . h_pi   via K=8 fp16 slots:
//  A[j] (scan side) = [hqx,hqy,hqz, eqx,eqy,eqz, qs_h, qs_e]
//  B[i] (held side) = [-2hpx,-2hpy,-2hpz, -2hpx,-2hpy,-2hpz, 1, 1]
//  products: k0-2 h_q*(-2h_p), k3-5 e_q*(-2h_p), k6-7 qs
// Then D[j,i] = E + |p_i|^2 added in fp32 in the EPILOGUE (exact, per src
// point, constant inside the min over j). Dropped term -2 q.e_p ~ 3e-3
// << 0.0675 threshold. fp16*fp16 exact in fp32 accumulator.
// 16B per point per form -> half the bytes of the R7-R15 K=13 packing.

__global__ void prep_k8(const float* __restrict__ x1, const float* __restrict__ x2,
                        _Float16* __restrict__ pa1, _Float16* __restrict__ pb1, float* __restrict__ ps1,
                        _Float16* __restrict__ pa2, _Float16* __restrict__ pb2, float* __restrict__ ps2,
                        float* __restrict__ out, int n1, int n2, int outn) {
    const int i = blockIdx.x * blockDim.x + threadIdx.x;
    const _Float16 one = (_Float16)1.0f;

    #pragma unroll
    for (int which = 0; which < 2; ++which) {
        const int n = which ? n2 : n1;
        if (i >= n) continue;
        const float* xp = (which ? x2 : x1) + 3 * (size_t)i;
        _Float16* pa = (which ? pa2 : pa1) + 8 * (size_t)i;
        _Float16* pb = (which ? pb2 : pb1) + 8 * (size_t)i;
        float* ps    = (which ? ps2 : ps1);

        const float x = xp[0], y = xp[1], z = xp[2];
        const _Float16 hx = (_Float16)x, hy = (_Float16)y, hz = (_Float16)z;
        const _Float16 ex = (_Float16)(x - (float)hx);
        const _Float16 ey = (_Float16)(y - (float)hy);
        const _Float16 ez = (_Float16)(z - (float)hz);
        const float sq = fmaf(x, x, fmaf(y, y, z * z));
        const _Float16 qh = (_Float16)sq;
        const _Float16 qe = (_Float16)(sq - (float)qh);
        const _Float16 tx = (_Float16)(-2.0f * (float)hx);
        const _Float16 ty = (_Float16)(-2.0f * (float)hy);
        const _Float16 tz = (_Float16)(-2.0f * (float)hz);

        *(half8*)pa = (half8){hx, hy, hz, ex, ey, ez, qh, qe};   // A-form, 16B
        *(half8*)pb = (half8){tx, ty, tz, tx, ty, tz, one, one}; // B-form, 16B
        ps[i] = sq;                                              // fp32 exact
    }
    if (i < outn) out[i] = FLT_MAX;
}

// Fold 16 fresh values + running min into one scalar: ~8 v_min3-class ops.
__device__ inline float min16_into(float r, const f32x16 d) {
    const float t0 = fminf(fminf(d[0],  d[1]),  d[2]);
    const float t1 = fminf(fminf(d[3],  d[4]),  d[5]);
    const float t2 = fminf(fminf(d[6],  d[7]),  d[8]);
    const float t3 = fminf(fminf(d[9],  d[10]), d[11]);
    const float t4 = fminf(fminf(d[12], d[13]), d[14]);
    const float u0 = fminf(fminf(t0, t1), t2);
    const float u1 = fminf(fminf(t3, t4), d[15]);
    return fminf(fminf(r, u0), u1);
}

// R16: LDS-free (R13-proven), K=8, IT=4.
// Block = 4 waves x 128 cols = 512 src cols; sweeps jseg = N/NJ scan rows
// straight from global (L2-resident; 2MB total packed data). Per a-load
// (8B dwordx2): 4 independent MFMAs + 4 min-trees -> 1/4 the loads/MFMA of
// R11-R15. No barriers, no LDS: waves fully independent, TLP hides latency.
// NOTE: plain __launch_bounds__(256) — R5/R9: min-waves args spill f32x16.
// Layouts (32x32 family, m74/m101 + R8-R15 verified): A frag row=lane&31,
// k=4*(lane>>5)+j; B frag col=lane&31; D col=lane&31, rows: lane and
// lane^32 cover all 32 rows (only this + col identity is relied upon).
template<int NJ>
__global__ __launch_bounds__(256) void chamfer_k8(
        const _Float16* __restrict__ pa1, const _Float16* __restrict__ pb1,
        const float* __restrict__ ps1,
        const _Float16* __restrict__ pa2, const _Float16* __restrict__ pb2,
        const float* __restrict__ ps2,
        float* __restrict__ out, int N) {
    constexpr int IT = 4;

    const int tid  = threadIdx.x;
    const int lane = tid & 63;
    const int w    = tid >> 6;

    int bid = blockIdx.x;
    const int CB      = N / 512;          // col-blocks per batch
    const int per_dir = BATCH * CB * NJ;
    const int dir = bid / per_dir;   bid %= per_dir;
    const int b   = bid / (CB * NJ); bid %= (CB * NJ);
    const int cb  = bid / NJ;
    const int js  = bid % NJ;

    // dir0: held src = set1 (B-form + ps1), scan = set2 (A-form)
    const _Float16* pstream = dir ? pa1 : pa2;
    const _Float16* pheld   = dir ? pb2 : pb1;
    const float*    phps    = dir ? ps2 : ps1;
    float* outd = out + (size_t)dir * BATCH * N + (size_t)b * N;

    // Held B-fragments: 8B per lane, 4 tiles of 32 cols.
    const int colbase = cb * 512 + w * 128;
    const uint2* gh = (const uint2*)pheld;
    half4v bf[IT];
    #pragma unroll
    for (int it = 0; it < IT; ++it) {
        const int c = colbase + it * 32 + (lane & 31);
        bf[it] = __builtin_bit_cast(half4v, gh[(size_t)(b * N + c) * 2 + (lane >> 5)]);
    }

    float rmin[IT];
    #pragma unroll
    for (int it = 0; it < IT; ++it) rmin[it] = FLT_MAX;

    f32x16 cz;
    #pragma unroll
    for (int e = 0; e < 16; ++e) cz[e] = 0.0f;

    const int jseg   = N / NJ;
    const int ntiles = jseg / 32;
    const uint2* gs  = (const uint2*)pstream;
    // lane's fixed A-fragment address within a tile (uint2 = 8B units)
    const size_t abase = (size_t)(b * N + js * jseg) * 2
                       + (size_t)(lane & 31) * 2 + (lane >> 5);

    #pragma unroll 2
    for (int tt = 0; tt < ntiles; ++tt) {
        const half4v a = __builtin_bit_cast(half4v, gs[abase + (size_t)tt * 64]);
        #pragma unroll
        for (int it = 0; it < IT; ++it) {
            const f32x16 d = __builtin_amdgcn_mfma_f32_32x32x8f16(a, bf[it], cz, 0, 0, 0);
            rmin[it] = min16_into(rmin[it], d);
        }
    }

    // epilogue: combine row-halves, add src |p|^2 (fp32 exact), atomicMin.
    #pragma unroll
    for (int it = 0; it < IT; ++it) {
        const float v = fminf(rmin[it], __shfl_xor(rmin[it], 32, 64));
        if (lane < 32) {
            const int c = colbase + it * 32 + lane;
            const float dfin = fmaxf(v + phps[(size_t)b * N + c], 0.0f);
            atomicMin((int*)&outd[c], __float_as_int(dfin));
        }
    }
}

// ================= fallback: R6 pk-fma path =================
__global__ void chamfer_prep(const float* __restrict__ xyz1,
                             const float* __restrict__ xyz2,
                             float4* __restrict__ pk1,
                             float4* __restrict__ pk2,
                             float* __restrict__ out,
                             int n1, int n2, int out_n) {
    int i = blockIdx.x * blockDim.x + threadIdx.x;
    if (i < n1) {
        float x = xyz1[3 * (size_t)i], y = xyz1[3 * (size_t)i + 1], z = xyz1[3 * (size_t)i + 2];
        pk1[i] = make_float4(-2.f * x, -2.f * y, -2.f * z, fmaf(x, x, fmaf(y, y, z * z)));
    }
    if (i < n2) {
        float x = xyz2[3 * (size_t)i], y = xyz2[3 * (size_t)i + 1], z = xyz2[3 * (size_t)i + 2];
        pk2[i] = make_float4(-2.f * x, -2.f * y, -2.f * z, fmaf(x, x, fmaf(y, y, z * z)));
    }
    if (i < out_n) out[i] = FLT_MAX;
}

template<int TPB, int CHUNK, int P>
__global__ __launch_bounds__(TPB) void chamfer_fused(
        const float* __restrict__ xyz1, const float* __restrict__ xyz2,
        const float4* __restrict__ pk1, const float4* __restrict__ pk2,
        float* __restrict__ out, int N, int M, int blocks_dir0) {
    __shared__ float4 s[CHUNK];
    int bid = blockIdx.x;
    const int dir = (bid >= blocks_dir0) ? 1 : 0;
    if (dir) bid -= blocks_dir0;
    const int Nsrc = dir ? M : N;
    const int Mdst = dir ? N : M;
    const float* src   = dir ? xyz2 : xyz1;
    const float4* dstp = dir ? pk1  : pk2;
    float* outd        = dir ? (out + (size_t)BATCH * N) : out;
    const int YT = Nsrc / (TPB * P);
    const int Z  = Mdst / CHUNK;
    const int b  = bid / (YT * Z);
    const int r  = bid % (YT * Z);
    const int yt = r / Z;
    const int z  = r % Z;
    const float4* dchunk = dstp + (size_t)b * Mdst + (size_t)z * CHUNK;
    for (int t = threadIdx.x; t < CHUNK / 2; t += TPB) {
        const float4 q0 = dchunk[2 * t];
        const float4 q1 = dchunk[2 * t + 1];
        s[2 * t]     = make_float4(q0.x, q1.x, q0.y, q1.y);
        s[2 * t + 1] = make_float4(q0.z, q1.z, q0.w, q1.w);
    }
    const int i0 = yt * (TPB * P) + threadIdx.x;
    f32x2 px[P], py[P], pz[P];
    float psq[P], m[P];
    #pragma unroll
    for (int k = 0; k < P; ++k) {
        const int i = i0 + k * TPB;
        const float* p = src + ((size_t)b * Nsrc + i) * 3;
        const float x = p[0], y = p[1], zc = p[2];
        px[k] = (f32x2){x, x}; py[k] = (f32x2){y, y}; pz[k] = (f32x2){zc, zc};
        psq[k] = fmaf(x, x, fmaf(y, y, zc * zc));
        m[k] = FLT_MAX;
    }
    __syncthreads();
    #pragma unroll 8
    for (int jj = 0; jj < CHUNK / 2; ++jj) {
        const float4 A = s[2 * jj];
        const float4 B = s[2 * jj + 1];
        const f32x2 xq = (f32x2){A.x, A.y};
        const f32x2 yq = (f32x2){A.z, A.w};
        const f32x2 zq = (f32x2){B.x, B.y};
        const f32x2 wq = (f32x2){B.z, B.w};
        #pragma unroll
        for (int k = 0; k < P; ++k) {
            const f32x2 e = __builtin_elementwise_fma(xq, px[k],
                             __builtin_elementwise_fma(yq, py[k],
                              __builtin_elementwise_fma(zq, pz[k], wq)));
            m[k] = fminf(fminf(m[k], e.x), e.y);
        }
    }
    #pragma unroll
    for (int k = 0; k < P; ++k) {
        const int i = i0 + k * TPB;
        const float d = fmaxf(psq[k] + m[k], 0.0f);
        atomicMin((int*)&outd[(size_t)b * Nsrc + i], __float_as_int(d));
    }
}

extern "C" void kernel_launch(void* const* d_in, const int* in_sizes, int n_in,
                              void* d_out, int out_size, void* d_ws, size_t ws_size,
                              hipStream_t stream) {
    const float* xyz1 = (const float*)d_in[0];
    const float* xyz2 = (const float*)d_in[1];
    float* out = (float*)d_out;

    const int N = in_sizes[0] / (BATCH * 3);  // 8192
    const int M = in_sizes[1] / (BATCH * 3);  // 8192
    const int n1 = BATCH * N, n2 = BATCH * M;

    constexpr int TPB = 256;
    constexpr int NJ = 16;

    // ws layout: pa1|pb1|pa2|pb2 (16B/pt each), then ps1|ps2 (4B/pt)
    const size_t need = ((size_t)n1 + (size_t)n2) * 36;
    const bool mfma_ok = (N == M) && (N % 512 == 0) && (N % (NJ * 32) == 0) &&
                         (ws_size >= need);

    if (mfma_ok) {
        _Float16* pa1 = (_Float16*)d_ws;
        _Float16* pb1 = pa1 + (size_t)n1 * 8;
        _Float16* pa2 = pb1 + (size_t)n1 * 8;
        _Float16* pb2 = pa2 + (size_t)n2 * 8;
        float* ps1 = (float*)(pb2 + (size_t)n2 * 8);
        float* ps2 = ps1 + n1;

        int prep_n = out_size > n1 ? out_size : n1;
        if (n2 > prep_n) prep_n = n2;
        prep_k8<<<(prep_n + TPB - 1) / TPB, TPB, 0, stream>>>(
            xyz1, xyz2, pa1, pb1, ps1, pa2, pb2, ps2, out, n1, n2, out_size);

        const int grid = 2 * BATCH * (N / 512) * NJ;   // 2048
        chamfer_k8<NJ><<<grid, TPB, 0, stream>>>(
            pa1, pb1, ps1, pa2, pb2, ps2, out, N);
        return;
    }

    // fallback: R6 pk-fma path
    constexpr int CHUNK = 128;
    constexpr int P = 8;
    const size_t needf = ((size_t)n1 + (size_t)n2) * sizeof(float4);
    if (ws_size >= needf && (N % (TPB * P) == 0) && (M % (TPB * P) == 0) &&
        (N % CHUNK == 0) && (M % CHUNK == 0)) {
        float4* pk1 = (float4*)d_ws;
        float4* pk2 = pk1 + n1;
        int prep_n = out_size > n1 ? out_size : n1;
        if (n2 > prep_n) prep_n = n2;
        chamfer_prep<<<(prep_n + TPB - 1) / TPB, TPB, 0, stream>>>(
            xyz1, xyz2, pk1, pk2, out, n1, n2, out_size);
        const int blocks_dir0 = BATCH * (N / (TPB * P)) * (M / CHUNK);
        const int blocks_dir1 = BATCH * (M / (TPB * P)) * (N / CHUNK);
        chamfer_fused<TPB, CHUNK, P><<<blocks_dir0 + blocks_dir1, TPB, 0, stream>>>(
            xyz1, xyz2, pk1, pk2, out, N, M, blocks_dir0);
    }
}

// Round 18
// 33.521 us; speedup vs baseline: 18.9711x; 1.0105x over previous
//
#include <hip/hip_runtime.h>
#include <float.h>

#define BATCH 4

typedef _Float16 half4v __attribute__((ext_vector_type(4)));
typedef _Float16 half8 __attribute__((ext_vector_type(8)));
typedef float f32x16 __attribute__((ext_vector_type(16)));
typedef float f32x2 __attribute__((ext_vector_type(2)));

// ================= MFMA K=8 path (R16 structure, R18 = VGPR-pinned D) ======
// E[j,i] = qs_j - 2 q_j . h_pi   via K=8 fp16 slots:
//  A[j] (scan side) = [hqx,hqy,hqz, eqx,eqy,eqz, qs_h, qs_e]
//  B[i] (held side) = [-2hpx,-2hpy,-2hpz, -2hpx,-2hpy,-2hpz, 1, 1]
// D[j,i] = E + |p_i|^2 added in fp32 in the EPILOGUE. Dropped -2q.e_p ~1.6e-2
// << 0.0675 threshold (R16 measured absmax 0.0156).
//
// R17 lesson: raw inline-asm v_mfma loses the compiler's MFMA->VALU hazard
// nops (no HW interlock) -> garbage. R18 keeps the INTRINSIC (hazards
// handled) and pins the RESULT into arch VGPRs with an empty "+v" asm —
// "v" cannot be AGPR, so RA drops the per-MFMA 16x v_accvgpr_read fan-out
// (R15: 57 VALU inst/MFMA measured vs ~11 hand-counted; VGPR_Count=24 with
// 100+ live floats => state was in AGPRs).

__global__ void prep_k8(const float* __restrict__ x1, const float* __restrict__ x2,
                        _Float16* __restrict__ pa1, _Float16* __restrict__ pb1, float* __restrict__ ps1,
                        _Float16* __restrict__ pa2, _Float16* __restrict__ pb2, float* __restrict__ ps2,
                        float* __restrict__ out, int n1, int n2, int outn) {
    const int i = blockIdx.x * blockDim.x + threadIdx.x;
    const _Float16 one = (_Float16)1.0f;

    #pragma unroll
    for (int which = 0; which < 2; ++which) {
        const int n = which ? n2 : n1;
        if (i >= n) continue;
        const float* xp = (which ? x2 : x1) + 3 * (size_t)i;
        _Float16* pa = (which ? pa2 : pa1) + 8 * (size_t)i;
        _Float16* pb = (which ? pb2 : pb1) + 8 * (size_t)i;
        float* ps    = (which ? ps2 : ps1);

        const float x = xp[0], y = xp[1], z = xp[2];
        const _Float16 hx = (_Float16)x, hy = (_Float16)y, hz = (_Float16)z;
        const _Float16 ex = (_Float16)(x - (float)hx);
        const _Float16 ey = (_Float16)(y - (float)hy);
        const _Float16 ez = (_Float16)(z - (float)hz);
        const float sq = fmaf(x, x, fmaf(y, y, z * z));
        const _Float16 qh = (_Float16)sq;
        const _Float16 qe = (_Float16)(sq - (float)qh);
        const _Float16 tx = (_Float16)(-2.0f * (float)hx);
        const _Float16 ty = (_Float16)(-2.0f * (float)hy);
        const _Float16 tz = (_Float16)(-2.0f * (float)hz);

        *(half8*)pa = (half8){hx, hy, hz, ex, ey, ez, qh, qe};   // A-form, 16B
        *(half8*)pb = (half8){tx, ty, tz, tx, ty, tz, one, one}; // B-form, 16B
        ps[i] = sq;                                              // fp32 exact
    }
    if (i < outn) out[i] = FLT_MAX;
}

// Fold 16 fresh values + running min into one scalar: 8 v_min3-class ops.
__device__ inline float min16_into(float r, const f32x16 d) {
    const float t0 = fminf(fminf(d[0],  d[1]),  d[2]);
    const float t1 = fminf(fminf(d[3],  d[4]),  d[5]);
    const float t2 = fminf(fminf(d[6],  d[7]),  d[8]);
    const float t3 = fminf(fminf(d[9],  d[10]), d[11]);
    const float t4 = fminf(fminf(d[12], d[13]), d[14]);
    const float u0 = fminf(fminf(t0, t1), t2);
    const float u1 = fminf(fminf(t3, t4), d[15]);
    return fminf(fminf(r, u0), u1);
}

// R18: LDS-free (R13-proven), K=8, IT=4, VGPR-pinned MFMA result.
template<int NJ>
__global__ __launch_bounds__(256) void chamfer_k8(
        const _Float16* __restrict__ pa1, const _Float16* __restrict__ pb1,
        const float* __restrict__ ps1,
        const _Float16* __restrict__ pa2, const _Float16* __restrict__ pb2,
        const float* __restrict__ ps2,
        float* __restrict__ out, int N) {
    constexpr int IT = 4;

    const int tid  = threadIdx.x;
    const int lane = tid & 63;
    const int w    = tid >> 6;

    int bid = blockIdx.x;
    const int CB      = N / 512;          // col-blocks per batch
    const int per_dir = BATCH * CB * NJ;
    const int dir = bid / per_dir;   bid %= per_dir;
    const int b   = bid / (CB * NJ); bid %= (CB * NJ);
    const int cb  = bid / NJ;
    const int js  = bid % NJ;

    const _Float16* pstream = dir ? pa1 : pa2;
    const _Float16* pheld   = dir ? pb2 : pb1;
    const float*    phps    = dir ? ps2 : ps1;
    float* outd = out + (size_t)dir * BATCH * N + (size_t)b * N;

    // Held B-fragments: 8B per lane, 4 tiles of 32 cols.
    const int colbase = cb * 512 + w * 128;
    const uint2* gh = (const uint2*)pheld;
    half4v bf[IT];
    #pragma unroll
    for (int it = 0; it < IT; ++it) {
        const int c = colbase + it * 32 + (lane & 31);
        bf[it] = __builtin_bit_cast(half4v, gh[(size_t)(b * N + c) * 2 + (lane >> 5)]);
    }

    float rmin[IT];
    #pragma unroll
    for (int it = 0; it < IT; ++it) rmin[it] = FLT_MAX;

    f32x16 cz;
    #pragma unroll
    for (int e = 0; e < 16; ++e) cz[e] = 0.0f;

    const int jseg   = N / NJ;
    const int ntiles = jseg / 32;
    const uint2* gs  = (const uint2*)pstream;
    const size_t abase = (size_t)(b * N + js * jseg) * 2
                       + (size_t)(lane & 31) * 2 + (lane >> 5);

    #pragma unroll 2
    for (int tt = 0; tt < ntiles; ++tt) {
        const half4v a = __builtin_bit_cast(half4v, gs[abase + (size_t)tt * 64]);
        #pragma unroll
        for (int it = 0; it < IT; ++it) {
            f32x16 d = __builtin_amdgcn_mfma_f32_32x32x8f16(a, bf[it], cz, 0, 0, 0);
            // Pin D into arch VGPRs ("v" cannot be AGPR): RA coalesces the
            // MFMA dst to VGPRs, deleting 16x v_accvgpr_read per MFMA.
            // Intrinsic (not asm-mfma) keeps compiler hazard handling (R17!).
            asm volatile("" : "+v"(d));
            rmin[it] = min16_into(rmin[it], d);
        }
    }

    // epilogue: combine row-halves, add src |p|^2 (fp32 exact), atomicMin.
    #pragma unroll
    for (int it = 0; it < IT; ++it) {
        const float v = fminf(rmin[it], __shfl_xor(rmin[it], 32, 64));
        if (lane < 32) {
            const int c = colbase + it * 32 + lane;
            const float dfin = fmaxf(v + phps[(size_t)b * N + c], 0.0f);
            atomicMin((int*)&outd[c], __float_as_int(dfin));
        }
    }
}

// ================= fallback: R6 pk-fma path =================
__global__ void chamfer_prep(const float* __restrict__ xyz1,
                             const float* __restrict__ xyz2,
                             float4* __restrict__ pk1,
                             float4* __restrict__ pk2,
                             float* __restrict__ out,
                             int n1, int n2, int out_n) {
    int i = blockIdx.x * blockDim.x + threadIdx.x;
    if (i < n1) {
        float x = xyz1[3 * (size_t)i], y = xyz1[3 * (size_t)i + 1], z = xyz1[3 * (size_t)i + 2];
        pk1[i] = make_float4(-2.f * x, -2.f * y, -2.f * z, fmaf(x, x, fmaf(y, y, z * z)));
    }
    if (i < n2) {
        float x = xyz2[3 * (size_t)i], y = xyz2[3 * (size_t)i + 1], z = xyz2[3 * (size_t)i + 2];
        pk2[i] = make_float4(-2.f * x, -2.f * y, -2.f * z, fmaf(x, x, fmaf(y, y, z * z)));
    }
    if (i < out_n) out[i] = FLT_MAX;
}

template<int TPB, int CHUNK, int P>
__global__ __launch_bounds__(TPB) void chamfer_fused(
        const float* __restrict__ xyz1, const float* __restrict__ xyz2,
        const float4* __restrict__ pk1, const float4* __restrict__ pk2,
        float* __restrict__ out, int N, int M, int blocks_dir0) {
    __shared__ float4 s[CHUNK];
    int bid = blockIdx.x;
    const int dir = (bid >= blocks_dir0) ? 1 : 0;
    if (dir) bid -= blocks_dir0;
    const int Nsrc = dir ? M : N;
    const int Mdst = dir ? N : M;
    const float* src   = dir ? xyz2 : xyz1;
    const float4* dstp = dir ? pk1  : pk2;
    float* outd        = dir ? (out + (size_t)BATCH * N) : out;
    const int YT = Nsrc / (TPB * P);
    const int Z  = Mdst / CHUNK;
    const int b  = bid / (YT * Z);
    const int r  = bid % (YT * Z);
    const int yt = r / Z;
    const int z  = r % Z;
    const float4* dchunk = dstp + (size_t)b * Mdst + (size_t)z * CHUNK;
    for (int t = threadIdx.x; t < CHUNK / 2; t += TPB) {
        const float4 q0 = dchunk[2 * t];
        const float4 q1 = dchunk[2 * t + 1];
        s[2 * t]     = make_float4(q0.x, q1.x, q0.y, q1.y);
        s[2 * t + 1] = make_float4(q0.z, q1.z, q0.w, q1.w);
    }
    const int i0 = yt * (TPB * P) + threadIdx.x;
    f32x2 px[P], py[P], pz[P];
    float psq[P], m[P];
    #pragma unroll
    for (int k = 0; k < P; ++k) {
        const int i = i0 + k * TPB;
        const float* p = src + ((size_t)b * Nsrc + i) * 3;
        const float x = p[0], y = p[1], zc = p[2];
        px[k] = (f32x2){x, x}; py[k] = (f32x2){y, y}; pz[k] = (f32x2){zc, zc};
        psq[k] = fmaf(x, x, fmaf(y, y, zc * zc));
        m[k] = FLT_MAX;
    }
    __syncthreads();
    #pragma unroll 8
    for (int jj = 0; jj < CHUNK / 2; ++jj) {
        const float4 A = s[2 * jj];
        const float4 B = s[2 * jj + 1];
        const f32x2 xq = (f32x2){A.x, A.y};
        const f32x2 yq = (f32x2){A.z, A.w};
        const f32x2 zq = (f32x2){B.x, B.y};
        const f32x2 wq = (f32x2){B.z, B.w};
        #pragma unroll
        for (int k = 0; k < P; ++k) {
            const f32x2 e = __builtin_elementwise_fma(xq, px[k],
                             __builtin_elementwise_fma(yq, py[k],
                              __builtin_elementwise_fma(zq, pz[k], wq)));
            m[k] = fminf(fminf(m[k], e.x), e.y);
        }
    }
    #pragma unroll
    for (int k = 0; k < P; ++k) {
        const int i = i0 + k * TPB;
        const float d = fmaxf(psq[k] + m[k], 0.0f);
        atomicMin((int*)&outd[(size_t)b * Nsrc + i], __float_as_int(d));
    }
}

extern "C" void kernel_launch(void* const* d_in, const int* in_sizes, int n_in,
                              void* d_out, int out_size, void* d_ws, size_t ws_size,
                              hipStream_t stream) {
    const float* xyz1 = (const float*)d_in[0];
    const float* xyz2 = (const float*)d_in[1];
    float* out = (float*)d_out;

    const int N = in_sizes[0] / (BATCH * 3);  // 8192
    const int M = in_sizes[1] / (BATCH * 3);  // 8192
    const int n1 = BATCH * N, n2 = BATCH * M;

    constexpr int TPB = 256;
    constexpr int NJ = 16;

    // ws layout: pa1|pb1|pa2|pb2 (16B/pt each), then ps1|ps2 (4B/pt)
    const size_t need = ((size_t)n1 + (size_t)n2) * 36;
    const bool mfma_ok = (N == M) && (N % 512 == 0) && (N % (NJ * 32) == 0) &&
                         (ws_size >= need);

    if (mfma_ok) {
        _Float16* pa1 = (_Float16*)d_ws;
        _Float16* pb1 = pa1 + (size_t)n1 * 8;
        _Float16* pa2 = pb1 + (size_t)n1 * 8;
        _Float16* pb2 = pa2 + (size_t)n2 * 8;
        float* ps1 = (float*)(pb2 + (size_t)n2 * 8);
        float* ps2 = ps1 + n1;

        int prep_n = out_size > n1 ? out_size : n1;
        if (n2 > prep_n) prep_n = n2;
        prep_k8<<<(prep_n + TPB - 1) / TPB, TPB, 0, stream>>>(
            xyz1, xyz2, pa1, pb1, ps1, pa2, pb2, ps2, out, n1, n2, out_size);

        const int grid = 2 * BATCH * (N / 512) * NJ;   // 2048
        chamfer_k8<NJ><<<grid, TPB, 0, stream>>>(
            pa1, pb1, ps1, pa2, pb2, ps2, out, N);
        return;
    }

    // fallback: R6 pk-fma path
    constexpr int CHUNK = 128;
    constexpr int P = 8;
    const size_t needf = ((size_t)n1 + (size_t)n2) * sizeof(float4);
    if (ws_size >= needf && (N % (TPB * P) == 0) && (M % (TPB * P) == 0) &&
        (N % CHUNK == 0) && (M % CHUNK == 0)) {
        float4* pk1 = (float4*)d_ws;
        float4* pk2 = pk1 + n1;
        int prep_n = out_size > n1 ? out_size : n1;
        if (n2 > prep_n) prep_n = n2;
        chamfer_prep<<<(prep_n + TPB - 1) / TPB, TPB, 0, stream>>>(
            xyz1, xyz2, pk1, pk2, out, n1, n2, out_size);
        const int blocks_dir0 = BATCH * (N / (TPB * P)) * (M / CHUNK);
        const int blocks_dir1 = BATCH * (M / (TPB * P)) * (N / CHUNK);
        chamfer_fused<TPB, CHUNK, P><<<blocks_dir0 + blocks_dir1, TPB, 0, stream>>>(
            xyz1, xyz2, pk1, pk2, out, N, M, blocks_dir0);
    }
}